// Round 17
// baseline (27.409 us; speedup 1.0000x reference)
//
#include <hip/hip_runtime.h>
#include <cstdint>
#include <cstddef>

typedef _Float16 half8 __attribute__((ext_vector_type(8)));
typedef float f32x4 __attribute__((ext_vector_type(4)));

static constexpr int kN = 256;           // state dim (N == K)

// Pack A_stacked[t] (fp32 [n][k]) into f16 frag order, ks-chunk-major:
// unit u = ks*16 + nt (1 KiB each): a16[(u*64 + l)*8 + j]
//   = A[nt*16 + (l&15)][ks*32 + (l>>4)*8 + j]
// -> chunk ks is a contiguous 16 KiB block.
__global__ __launch_bounds__(256) void hippo_prep(
    const float* __restrict__ A_stacked, const int* __restrict__ tptr,
    _Float16* __restrict__ a16)
{
    const int t = tptr[0];
    const float* __restrict__ A = A_stacked + (size_t)t * kN * kN;
    const int tid = blockIdx.x * 256 + threadIdx.x;   // 0..8191
    const int u  = tid >> 6;         // 0..127 = ks*16 + nt
    const int l  = tid & 63;
    const int ks = u >> 4;
    const int nt = u & 15;
    const int row = nt * 16 + (l & 15);
    const int k0  = ks * 32 + ((l >> 4) << 3);
    const float* __restrict__ src = A + (size_t)row * kN + k0;
    f32x4 v0 = *(const f32x4*)(src);
    f32x4 v1 = *(const f32x4*)(src + 4);
    half8 h;
    h[0] = (_Float16)v0[0]; h[1] = (_Float16)v0[1];
    h[2] = (_Float16)v0[2]; h[3] = (_Float16)v0[3];
    h[4] = (_Float16)v1[0]; h[5] = (_Float16)v1[1];
    h[6] = (_Float16)v1[2]; h[7] = (_Float16)v1[3];
    ((half8*)a16)[tid] = h;
}

// out[m][n] = sum_k c[m][k] * A_t[n][k] + b[n] * f[m]
// 4 blocks/CU occupancy point: 256-thr blocks, 32 KiB LDS (2 x 16 KiB
// ks-chunk double buffer), waves = 2m x 2n (16 rows x 128 cols each,
// acc = 32 VGPR). Per k-chunk: issue next DMA + next c, compute current,
// sync. 16 desynced waves/CU overlap HBM reads/writes with LDS/MFMA.
__global__ __launch_bounds__(256, 4) void hippo_gemm(
    const float* __restrict__ c, const float* __restrict__ f,
    const float* __restrict__ Bst, const int* __restrict__ tptr,
    const _Float16* __restrict__ a16, float* __restrict__ out)
{
    __shared__ _Float16 As[2][8192];   // 2 x 16 KiB chunk buffers

    const int tid  = threadIdx.x;
    const int l    = tid & 63;
    const int wid  = tid >> 6;        // 0..3
    const int wm   = wid & 1;         // m-half (16 rows)
    const int wn   = wid >> 1;        // n-half (128 cols)
    const int lo16 = l & 15;
    const int hi4  = l >> 4;
    const int m0   = blockIdx.x * 32 + wm * 16;
    const int ntb  = wn * 8;          // first n-tile (of 16) for this wave

    const char* __restrict__ gsrc = (const char*)a16;

    // ---- DMA chunk 0 into buf 0 (wave stages 4 x 1 KiB) ----
    #pragma unroll
    for (int i = 0; i < 4; ++i) {
        const size_t off = (size_t)(i * 4 + wid) * 1024 + (size_t)l * 16;
        __builtin_amdgcn_global_load_lds(
            (const __attribute__((address_space(1))) void*)(gsrc + off),
            (__attribute__((address_space(3))) void*)((char*)As[0] + off),
            16, 0, 0);
    }

    // ---- c chunk 0 ----
    const float* __restrict__ cptr = c + (size_t)(m0 + lo16) * kN + (hi4 << 3);
    f32x4 cv0 = *(const f32x4*)(cptr);
    f32x4 cv1 = *(const f32x4*)(cptr + 4);

    // ---- bias ----
    const int t = tptr[0];
    const float* __restrict__ brow = Bst + (size_t)t * kN + wn * 128;
    float bvs[8];
    #pragma unroll
    for (int nt = 0; nt < 8; ++nt) bvs[nt] = brow[nt * 16 + lo16];
    float fv[4];
    #pragma unroll
    for (int r = 0; r < 4; ++r) fv[r] = f[m0 + (hi4 << 2) + r];

    __syncthreads();   // chunk 0 + c0 ready

    f32x4 acc[8];
    #pragma unroll
    for (int i = 0; i < 8; ++i) acc[i] = (f32x4){0.f, 0.f, 0.f, 0.f};

    f32x4 dv0, dv1;
    #pragma unroll
    for (int ks = 0; ks < 8; ++ks) {
        const int cur = ks & 1;
        // issue next chunk DMA + next c BEFORE computing current chunk
        if (ks < 7) {
            const char* src = gsrc + (size_t)(ks + 1) * 16384;
            char* dst = (char*)As[cur ^ 1];
            #pragma unroll
            for (int i = 0; i < 4; ++i) {
                const size_t off = (size_t)(i * 4 + wid) * 1024 + (size_t)l * 16;
                __builtin_amdgcn_global_load_lds(
                    (const __attribute__((address_space(1))) void*)(src + off),
                    (__attribute__((address_space(3))) void*)(dst + off),
                    16, 0, 0);
            }
            dv0 = *(const f32x4*)(cptr + (ks + 1) * 32);
            dv1 = *(const f32x4*)(cptr + (ks + 1) * 32 + 4);
        }
        // cvt current c -> f16 frag
        half8 af;
        af[0] = (_Float16)cv0[0]; af[1] = (_Float16)cv0[1];
        af[2] = (_Float16)cv0[2]; af[3] = (_Float16)cv0[3];
        af[4] = (_Float16)cv1[0]; af[5] = (_Float16)cv1[1];
        af[6] = (_Float16)cv1[2]; af[7] = (_Float16)cv1[3];
        // 8 MFMA on current chunk (8 independent chains)
        const half8* __restrict__ Bb = (const half8*)As[cur];
        #pragma unroll
        for (int nt = 0; nt < 8; ++nt) {
            half8 bf = Bb[(ntb + nt) * 64 + l];
            acc[nt] = __builtin_amdgcn_mfma_f32_16x16x32_f16(af, bf, acc[nt], 0, 0, 0);
        }
        cv0 = dv0; cv1 = dv1;
        __syncthreads();   // chunk ks reads done; chunk ks+1 landed
    }

    // ---- epilogue ----
    float* __restrict__ obase = out + (size_t)(m0 + (hi4 << 2)) * kN + wn * 128 + lo16;
    #pragma unroll
    for (int nt = 0; nt < 8; ++nt) {
        #pragma unroll
        for (int r = 0; r < 4; ++r)
            obase[(size_t)r * kN + nt * 16] = acc[nt][r] + bvs[nt] * fv[r];
    }
}

extern "C" void kernel_launch(void* const* d_in, const int* in_sizes, int n_in,
                              void* d_out, int out_size, void* d_ws, size_t ws_size,
                              hipStream_t stream) {
    const float* c   = (const float*)d_in[0];
    const float* f   = (const float*)d_in[1];
    const float* A   = (const float*)d_in[2];
    const float* B   = (const float*)d_in[3];
    const int*   t   = (const int*)d_in[4];
    float* out = (float*)d_out;
    _Float16* a16 = (_Float16*)d_ws;   // 128 KiB packed A[t] f16, ks-chunk-major

    const int batch = in_sizes[0] / kN;   // 32768

    hipLaunchKernelGGL(hippo_prep, dim3(32), dim3(256), 0, stream, A, t, a16);
    hipLaunchKernelGGL(hippo_gemm, dim3(batch / 32), dim3(256), 0, stream,
                       c, f, B, t, a16, out);
}